// Round 1
// baseline (77.907 us; speedup 1.0000x reference)
//
#include <hip/hip_runtime.h>

// ContinuityLoss: loss = 0.01/(n(n-1)) * sum_ij exp(-|pi-pj|^2/2) * |oi-oj|
// points: [N,2] f32, outputs: [N,8] f32, scalar f32 out.
// Compute-bound (67M pairs, ~320KB input). Tiled pair loop:
//   - block = 256 threads, each thread owns MROW=4 rows in registers
//   - j-tile of TILE=128 columns staged in LDS, read wave-uniform (broadcast)
//   - fp32 per-thread accum -> fp64 block partials -> deterministic final reduce

constexpr int TILE = 128;  // columns per block tile
constexpr int MROW = 4;    // rows per thread (amortizes LDS broadcast reads)
constexpr int BLK  = 256;  // threads per block

__global__ __launch_bounds__(BLK) void cont_partial(
    const float* __restrict__ points, const float* __restrict__ outputs,
    double* __restrict__ partials)
{
    __shared__ float2 sp[TILE];
    __shared__ float4 so[TILE][2];

    const int tid = threadIdx.x;
    const int rb  = blockIdx.x;          // row block
    const int cb  = blockIdx.y;          // col block
    const int jbase = cb * TILE;

    // stage column tile (first TILE threads)
    if (tid < TILE) {
        int j = jbase + tid;
        sp[tid]    = reinterpret_cast<const float2*>(points)[j];
        so[tid][0] = reinterpret_cast<const float4*>(outputs)[j * 2 + 0];
        so[tid][1] = reinterpret_cast<const float4*>(outputs)[j * 2 + 1];
    }

    // per-thread rows (coalesced: stride BLK between the 4 rows)
    float2 p[MROW];
    float4 o0[MROW], o1[MROW];
    const int ibase = rb * BLK * MROW;
    #pragma unroll
    for (int k = 0; k < MROW; ++k) {
        int i = ibase + k * BLK + tid;
        p[k]  = reinterpret_cast<const float2*>(points)[i];
        o0[k] = reinterpret_cast<const float4*>(outputs)[i * 2 + 0];
        o1[k] = reinterpret_cast<const float4*>(outputs)[i * 2 + 1];
    }
    __syncthreads();

    float acc[MROW] = {0.f, 0.f, 0.f, 0.f};
    #pragma unroll 2
    for (int j = 0; j < TILE; ++j) {
        const float2 pj = sp[j];          // wave-uniform -> LDS broadcast
        const float4 a  = so[j][0];
        const float4 b  = so[j][1];
        #pragma unroll
        for (int k = 0; k < MROW; ++k) {
            float dx = p[k].x - pj.x;
            float dy = p[k].y - pj.y;
            float d2 = dx * dx + dy * dy;
            float w  = __expf(-0.5f * d2);
            float t, dd;
            t = o0[k].x - a.x; dd  = t * t;
            t = o0[k].y - a.y; dd += t * t;
            t = o0[k].z - a.z; dd += t * t;
            t = o0[k].w - a.w; dd += t * t;
            t = o1[k].x - b.x; dd += t * t;
            t = o1[k].y - b.y; dd += t * t;
            t = o1[k].z - b.z; dd += t * t;
            t = o1[k].w - b.w; dd += t * t;
            // diagonal j==i contributes 0 exactly (dd==0) -> no mask needed
            acc[k] += w * sqrtf(dd);
        }
    }

    float s = (acc[0] + acc[1]) + (acc[2] + acc[3]);
    #pragma unroll
    for (int off = 32; off > 0; off >>= 1)
        s += __shfl_down(s, off, 64);

    __shared__ float wpart[BLK / 64];
    if ((tid & 63) == 0) wpart[tid >> 6] = s;
    __syncthreads();
    if (tid == 0) {
        double d = 0.0;
        #pragma unroll
        for (int w = 0; w < BLK / 64; ++w) d += (double)wpart[w];
        partials[(size_t)cb * gridDim.x + rb] = d;
    }
}

__global__ __launch_bounds__(1024) void cont_final(
    const double* __restrict__ partials, int nparts,
    float* __restrict__ out, double scale)
{
    const int tid = threadIdx.x;
    double s = 0.0;
    for (int i = tid; i < nparts; i += 1024) s += partials[i];
    #pragma unroll
    for (int off = 32; off > 0; off >>= 1)
        s += __shfl_down(s, off, 64);

    __shared__ double ws[1024 / 64];
    if ((tid & 63) == 0) ws[tid >> 6] = s;
    __syncthreads();
    if (tid == 0) {
        double t = 0.0;
        #pragma unroll
        for (int w = 0; w < 1024 / 64; ++w) t += ws[w];
        out[0] = (float)(t * scale);
    }
}

extern "C" void kernel_launch(void* const* d_in, const int* in_sizes, int n_in,
                              void* d_out, int out_size, void* d_ws, size_t ws_size,
                              hipStream_t stream) {
    const float* points  = (const float*)d_in[0];
    const float* outputs = (const float*)d_in[1];
    float* out = (float*)d_out;

    const int n = in_sizes[0] / 2;                 // 8192
    const int rowBlocks = n / (BLK * MROW);        // 8
    const int colBlocks = n / TILE;                // 64
    const int nparts = rowBlocks * colBlocks;      // 512

    double* partials = (double*)d_ws;              // 512 * 8B = 4KB scratch

    dim3 grid(rowBlocks, colBlocks);
    cont_partial<<<grid, dim3(BLK), 0, stream>>>(points, outputs, partials);

    const double scale = 0.01 / ((double)n * (double)(n - 1));
    cont_final<<<1, 1024, 0, stream>>>(partials, nparts, out, scale);
}

// Round 5
// 53.114 us; speedup vs baseline: 1.4668x; 1.4668x over previous
//
#include <hip/hip_runtime.h>

// ContinuityLoss: loss = 0.01/(n(n-1)) * sum_{i!=j} exp(-|pi-pj|^2/2) * |oi-oj|
// points: [N,2] f32, outputs: [N,8] f32, scalar f32 out. N = 8192.
//
// VALU-bound (inputs = 320 KB, fully cache-resident; 67M pairs).
// R1 design (resubmitted R2/R3/R4 after infra failures):
//  - symmetry: only upper-triangular 256x256 tiles (528 of 1024), off-diag x2
//  - j-side operands are wave-uniform -> compiler promotes to s_load (SMEM),
//    no LDS staging at all
//  - packed fp32 (v_pk_*) via ext_vector_type for the 8-dim output diff
//  - raw v_sqrt_f32 / native exp (1 trans op each; threshold is 2% rel)
//  - fp32 per-thread partials -> fp64 block partials -> deterministic reduce

typedef float v2f __attribute__((ext_vector_type(2)));
typedef float v4f __attribute__((ext_vector_type(4)));

constexpr int BLK = 256;            // threads per block
constexpr int TS  = 256;            // tile side (rows and cols)
constexpr int K   = 8192 / TS;      // 32 tiles per dim
constexpr int NBLOCKS = K * (K + 1) / 2;  // 528 upper-triangular tiles

__global__ __launch_bounds__(BLK) void cont_pairs(
    const float* __restrict__ points, const float* __restrict__ outputs,
    double* __restrict__ partials)
{
    // decode linear block id -> upper-triangular tile (r, s), r <= s
    int b = blockIdx.x;
    int r = 0, base = 0;
    while (b >= base + (K - r)) { base += K - r; ++r; }
    const int s = r + (b - base);

    const int i     = r * TS + threadIdx.x;   // this thread's row
    const int jbase = s * TS;

    const v2f pi  = *reinterpret_cast<const v2f*>(points  + 2 * i);
    const v4f oi0 = *reinterpret_cast<const v4f*>(outputs + 8 * i);
    const v4f oi1 = *reinterpret_cast<const v4f*>(outputs + 8 * i + 4);

    float acc0 = 0.f, acc1 = 0.f;
    #pragma unroll 4
    for (int jj = 0; jj < TS; jj += 2) {
        {   // j = jbase + jj  (uniform index -> scalar loads)
            const int j = jbase + jj;
            const v2f pj = *reinterpret_cast<const v2f*>(points  + 2 * j);
            const v4f a  = *reinterpret_cast<const v4f*>(outputs + 8 * j);
            const v4f c  = *reinterpret_cast<const v4f*>(outputs + 8 * j + 4);
            v2f dp = pi - pj;
            float d2 = dp.x * dp.x + dp.y * dp.y;
            float w  = __expf(-0.5f * d2);
            v4f t0 = oi0 - a;
            v4f t1 = oi1 - c;
            v4f q  = t0 * t0;
            q += t1 * t1;
            float dd = (q.x + q.y) + (q.z + q.w);
            acc0 += w * __builtin_amdgcn_sqrtf(dd);   // i==j gives exactly 0
        }
        {   // j = jbase + jj + 1
            const int j = jbase + jj + 1;
            const v2f pj = *reinterpret_cast<const v2f*>(points  + 2 * j);
            const v4f a  = *reinterpret_cast<const v4f*>(outputs + 8 * j);
            const v4f c  = *reinterpret_cast<const v4f*>(outputs + 8 * j + 4);
            v2f dp = pi - pj;
            float d2 = dp.x * dp.x + dp.y * dp.y;
            float w  = __expf(-0.5f * d2);
            v4f t0 = oi0 - a;
            v4f t1 = oi1 - c;
            v4f q  = t0 * t0;
            q += t1 * t1;
            float dd = (q.x + q.y) + (q.z + q.w);
            acc1 += w * __builtin_amdgcn_sqrtf(dd);
        }
    }

    float sum = acc0 + acc1;
    #pragma unroll
    for (int off = 32; off > 0; off >>= 1)
        sum += __shfl_down(sum, off, 64);

    __shared__ float wpart[BLK / 64];
    if ((threadIdx.x & 63) == 0) wpart[threadIdx.x >> 6] = sum;
    __syncthreads();
    if (threadIdx.x == 0) {
        double d = 0.0;
        #pragma unroll
        for (int w = 0; w < BLK / 64; ++w) d += (double)wpart[w];
        partials[b] = (r < s) ? 2.0 * d : d;   // off-diagonal tiles counted twice
    }
}

__global__ __launch_bounds__(1024) void cont_final(
    const double* __restrict__ partials, int nparts,
    float* __restrict__ out, double scale)
{
    const int tid = threadIdx.x;
    double sum = 0.0;
    for (int i = tid; i < nparts; i += 1024) sum += partials[i];
    #pragma unroll
    for (int off = 32; off > 0; off >>= 1)
        sum += __shfl_down(sum, off, 64);

    __shared__ double ws[1024 / 64];
    if ((tid & 63) == 0) ws[tid >> 6] = sum;
    __syncthreads();
    if (tid == 0) {
        double t = 0.0;
        #pragma unroll
        for (int w = 0; w < 1024 / 64; ++w) t += ws[w];
        out[0] = (float)(t * scale);
    }
}

extern "C" void kernel_launch(void* const* d_in, const int* in_sizes, int n_in,
                              void* d_out, int out_size, void* d_ws, size_t ws_size,
                              hipStream_t stream) {
    const float* points  = (const float*)d_in[0];
    const float* outputs = (const float*)d_in[1];
    float* out = (float*)d_out;

    const int n = in_sizes[0] / 2;             // 8192
    double* partials = (double*)d_ws;          // NBLOCKS * 8B = 4224 B scratch

    cont_pairs<<<dim3(NBLOCKS), dim3(BLK), 0, stream>>>(points, outputs, partials);

    const double scale = 0.01 / ((double)n * (double)(n - 1));
    cont_final<<<1, 1024, 0, stream>>>(partials, NBLOCKS, out, scale);
}

// Round 7
// 29.404 us; speedup vs baseline: 2.6496x; 1.8064x over previous
//
#include <hip/hip_runtime.h>

// ContinuityLoss: loss = 0.01/(n(n-1)) * sum_{i!=j} exp(-|pi-pj|^2/2) * |oi-oj|
// points: [N,2] f32, outputs: [N,8] f32, scalar f32 out. N = 8192.
//
// R5 (resubmitted R6 after infra failure): fix R1's SMEM-latency bound
// (VALUBusy 35%, 2 waves/SIMD).
//  - triangular super-tiles: 16 panels of 512 rows -> 136 tiles, x8 col-chunks
//    of 64 -> 1088 blocks (~17 waves/CU, 2x R1's occupancy)
//  - MROW=2 rows/thread: 2x VALU work per j-side load
//  - j-chunk staged in LDS, read wave-uniform (broadcast, conflict-free)
//  - float2-packed diffs (v_pk_fma_f32), exp2 with folded constant, raw v_sqrt
//  - fp32 thread partials -> fp64 block partials -> deterministic final reduce

typedef float v2f __attribute__((ext_vector_type(2)));

constexpr int BLK    = 256;                 // threads per block
constexpr int MROW   = 2;                   // rows per thread
constexpr int PANEL  = BLK * MROW;          // 512 rows per panel
constexpr int K      = 8192 / PANEL;        // 16 panels
constexpr int NTILES = K * (K + 1) / 2;     // 136 upper-tri super-tiles
constexpr int CHUNK  = 64;                  // columns per block
constexpr int NCHUNK = PANEL / CHUNK;       // 8 chunks per super-tile
constexpr int NBLOCKS = NTILES * NCHUNK;    // 1088 blocks

__global__ __launch_bounds__(BLK) void cont_pairs(
    const float* __restrict__ points, const float* __restrict__ outputs,
    double* __restrict__ partials)
{
    const int b     = blockIdx.x;
    const int tile  = b >> 3;               // which (r,s) super-tile
    const int chunk = b & (NCHUNK - 1);     // which 64-col chunk within it

    // decode tile -> upper-triangular (r, s), r <= s  (uniform, <=16 iters)
    int r = 0, base = 0;
    while (tile >= base + (K - r)) { base += K - r; ++r; }
    const int s = r + (tile - base);

    const int jbase = s * PANEL + chunk * CHUNK;

    __shared__ v2f sp[CHUNK];
    __shared__ v2f so[CHUNK][4];

    if (threadIdx.x < CHUNK) {
        const int j = jbase + threadIdx.x;
        sp[threadIdx.x] = reinterpret_cast<const v2f*>(points)[j];
        const v2f* oj = reinterpret_cast<const v2f*>(outputs + 8 * j);
        so[threadIdx.x][0] = oj[0];
        so[threadIdx.x][1] = oj[1];
        so[threadIdx.x][2] = oj[2];
        so[threadIdx.x][3] = oj[3];
    }

    // this thread's MROW rows, registers (coalesced: rows k*BLK apart)
    v2f pi[MROW], oi[MROW][4];
    const int ibase = r * PANEL + threadIdx.x;
    #pragma unroll
    for (int k = 0; k < MROW; ++k) {
        const int i = ibase + k * BLK;
        pi[k] = reinterpret_cast<const v2f*>(points)[i];
        const v2f* o = reinterpret_cast<const v2f*>(outputs + 8 * i);
        oi[k][0] = o[0]; oi[k][1] = o[1]; oi[k][2] = o[2]; oi[k][3] = o[3];
    }
    __syncthreads();

    constexpr float kE = -0.72134752044f;   // -0.5 * log2(e)
    float acc[MROW] = {0.f, 0.f};

    #pragma unroll 4
    for (int j = 0; j < CHUNK; ++j) {
        const v2f pj = sp[j];               // wave-uniform -> LDS broadcast
        const v2f a0 = so[j][0];
        const v2f a1 = so[j][1];
        const v2f a2 = so[j][2];
        const v2f a3 = so[j][3];
        #pragma unroll
        for (int k = 0; k < MROW; ++k) {
            v2f dp = pi[k] - pj;
            v2f pr = dp * dp;
            float w = __builtin_amdgcn_exp2f((pr.x + pr.y) * kE);
            v2f t0 = oi[k][0] - a0;
            v2f t1 = oi[k][1] - a1;
            v2f t2 = oi[k][2] - a2;
            v2f t3 = oi[k][3] - a3;
            v2f q  = t0 * t0;
            q += t1 * t1;
            q += t2 * t2;
            q += t3 * t3;
            // i==j contributes exactly 0 (q==0) -> no diagonal mask needed
            acc[k] += w * __builtin_amdgcn_sqrtf(q.x + q.y);
        }
    }

    float sum = acc[0] + acc[1];
    #pragma unroll
    for (int off = 32; off > 0; off >>= 1)
        sum += __shfl_down(sum, off, 64);

    __shared__ float wpart[BLK / 64];
    if ((threadIdx.x & 63) == 0) wpart[threadIdx.x >> 6] = sum;
    __syncthreads();
    if (threadIdx.x == 0) {
        double d = 0.0;
        #pragma unroll
        for (int w = 0; w < BLK / 64; ++w) d += (double)wpart[w];
        partials[b] = (r < s) ? 2.0 * d : d;   // off-diagonal tiles count twice
    }
}

__global__ __launch_bounds__(1024) void cont_final(
    const double* __restrict__ partials, int nparts,
    float* __restrict__ out, double scale)
{
    const int tid = threadIdx.x;
    double sum = 0.0;
    for (int i = tid; i < nparts; i += 1024) sum += partials[i];
    #pragma unroll
    for (int off = 32; off > 0; off >>= 1)
        sum += __shfl_down(sum, off, 64);

    __shared__ double ws[1024 / 64];
    if ((tid & 63) == 0) ws[tid >> 6] = sum;
    __syncthreads();
    if (tid == 0) {
        double t = 0.0;
        #pragma unroll
        for (int w = 0; w < 1024 / 64; ++w) t += ws[w];
        out[0] = (float)(t * scale);
    }
}

extern "C" void kernel_launch(void* const* d_in, const int* in_sizes, int n_in,
                              void* d_out, int out_size, void* d_ws, size_t ws_size,
                              hipStream_t stream) {
    const float* points  = (const float*)d_in[0];
    const float* outputs = (const float*)d_in[1];
    float* out = (float*)d_out;

    const int n = in_sizes[0] / 2;             // 8192
    double* partials = (double*)d_ws;          // 1088 * 8B = 8704 B scratch

    cont_pairs<<<dim3(NBLOCKS), dim3(BLK), 0, stream>>>(points, outputs, partials);

    const double scale = 0.01 / ((double)n * (double)(n - 1));
    cont_final<<<1, 1024, 0, stream>>>(partials, NBLOCKS, out, scale);
}